// Round 4
// baseline (749.824 us; speedup 1.0000x reference)
//
#include <hip/hip_runtime.h>

// CTC batch cost (keras ctc_batch_cost), forward alpha recursion.
// B=128, T=512, C=1024, L=64, S=2L+1=129, blank = C-1.
//
// One wave (64 lanes) per batch element. Lane i owns extended states
// {2i, 2i+1}; lane 63 also owns state 128. The only cross-lane dependency
// per step is state 2i-1 = lane (i-1)'s hi register; it moves via DPP
// wave_shr:1 (single v_mov_b32_dpp, ~6 cy) instead of ds_bpermute.
// No LDS, no __syncthreads, so the depth-24 register emission-prefetch
// ring (48 outstanding global loads, < vmcnt cap 63) stays in flight and
// covers the ~900 cy HBM gather latency (24 iters x ~60 cy > 900 cy).
//
// Recursion runs in log2 domain (v_exp_f32/v_log_f32 are base-2 HW ops);
// ln-domain alpha = log2-domain alpha * ln2 exactly (max/+/lse are
// scale-equivariant), restored at the final loss.
//
// R3 bugfix: skip transition for odd state s=2i+1 reads s-2 = 2i-1 =
// previous lane's HI register (was wrongly p_lo = state 2i-2).
//
// Inputs (setup_inputs order):
//   d_in[0] y_true       int32 [B,L]
//   d_in[1] y_pred       float [B,T,C]
//   d_in[2] input_length int32 [B,1]
//   d_in[3] label_length int32 [B,1]
// Output: float [B,1]

constexpr int Tmax   = 512;
constexpr int Cch    = 1024;
constexpr int Lm     = 64;
constexpr int BLANKC = Cch - 1;
constexpr int PF     = 24;   // prefetch depth; 2*PF=48 outstanding loads < 63

#define NEGF (-1e9f)
#define EPSF (1e-7f)
#define LN2F (0.69314718055994530942f)

// whole-wave shift right by 1 lane: result[i] = src[i-1], result[0] = fill.
// DPP ctrl 0x138 = wave_shr:1 (gfx9/CDNA), bound_ctrl=0 -> invalid lanes keep old.
__device__ __forceinline__ float wave_shr1(float src, float fill) {
    int r = __builtin_amdgcn_update_dpp(__float_as_int(fill), __float_as_int(src),
                                        0x138, 0xf, 0xf, false);
    return __int_as_float(r);
}

__device__ __forceinline__ float lae2(float a, float b) {
    float m = fmaxf(a, b);
    return m + __builtin_log2f(__builtin_exp2f(a - m) + __builtin_exp2f(b - m));
}
__device__ __forceinline__ float lse3_2(float a, float b, float c) {
    float m = fmaxf(fmaxf(a, b), c);
    return m + __builtin_log2f(__builtin_exp2f(a - m) +
                               __builtin_exp2f(b - m) +
                               __builtin_exp2f(c - m));
}

__global__ __launch_bounds__(64, 1) void ctc_wave(
    const int*   __restrict__ y_true,
    const float* __restrict__ y_pred,
    const int*   __restrict__ in_len,
    const int*   __restrict__ lab_len,
    float*       __restrict__ out)
{
    const int b    = blockIdx.x;
    const int lane = threadIdx.x;           // 0..63

    // label for odd state 2*lane+1
    const int cls = y_true[b * Lm + lane];

    int Tb = in_len[b];  Tb = Tb < 0 ? 0 : (Tb > Tmax ? Tmax : Tb);
    int lb = lab_len[b]; lb = lb < 0 ? 0 : (lb > Lm ? Lm : lb);

    // skip (s-2 -> s) for odd state 2i+1: allowed iff i>=1 and label differs
    const int  cls_prev = __shfl_up(cls, 1, 64);
    const bool skip     = (lane >= 1) && (cls != cls_prev);

    // validity masks (state s valid iff s < 2*lb+1)
    const bool val_lo = (lane <= lb);        // state 2*lane
    const bool val_hi = (lane <  lb);        // state 2*lane+1
    const bool val_ex = (lb == Lm);          // state 128 (lane 63 only)

    // virtual alpha_{-1}: mass only at state 0
    float a_lo = (lane == 0) ? 0.f : NEGF;
    float a_hi = NEGF;
    float a_ex = NEGF;

    const float* __restrict__ base = y_pred + (size_t)b * Tmax * Cch;

    // emission prefetch ring: label prob + blank prob per step
    float pf_c[PF], pf_b[PF];
#pragma unroll
    for (int i = 0; i < PF; ++i) {
        const float* row = base + (size_t)i * Cch;   // i < PF <= Tmax
        pf_c[i] = row[cls];
        pf_b[i] = row[BLANKC];
    }

    for (int t0 = 0; t0 < Tb; t0 += PF) {
#pragma unroll
        for (int i = 0; i < PF; ++i) {
            const int t = t0 + i;
            if (t >= Tb) break;              // Tb is wave-uniform

            const float e_c = __builtin_log2f(pf_c[i] + EPSF);
            const float e_b = __builtin_log2f(pf_b[i] + EPSF);

            // refill this ring slot for t+PF (row clamped; loads past Tb
            // are harmless, buffer extends to Tmax)
            {
                int tp = t + PF; int tr = tp < Tmax ? tp : Tmax - 1;
                const float* row = base + (size_t)tr * Cch;
                pf_c[i] = row[cls];
                pf_b[i] = row[BLANKC];
            }

            // state 2i-1 (prev lane's odd state) via whole-wave DPP shift
            const float p_hi = wave_shr1(a_hi, NEGF);

            // state 2i (blank): from self (2i) and 2i-1
            float n_lo = e_b + lae2(a_lo, p_hi);
            // state 2i+1 (label): from self, 2i (local lo), 2i-1 via skip
            float n_hi = e_c + lse3_2(a_hi, a_lo, skip ? p_hi : NEGF);
            // state 128 (blank, lane 63): from self and 127 (local hi)
            float n_ex = e_b + lae2(a_ex, a_hi);

            a_lo = val_lo ? n_lo : NEGF;
            a_hi = val_hi ? n_hi : NEGF;
            a_ex = val_ex ? n_ex : NEGF;
        }
    }

    // gather final states: eb = 2*lb, el = 2*lb-1
    const float a_end_blank = (lb == Lm) ? __shfl(a_ex, 63, 64)
                                         : __shfl(a_lo, lb, 64);
    const int   el_lane     = (lb >= 1) ? (lb - 1) : 0;
    const float a_end_label = (lb >= 1) ? __shfl(a_hi, el_lane, 64)
                                        : __shfl(a_lo, 0, 64);  // clamp s=0

    if (lane == 0) {
        out[b] = -LN2F * lae2(a_end_blank, a_end_label);
    }
}

extern "C" void kernel_launch(void* const* d_in, const int* in_sizes, int n_in,
                              void* d_out, int out_size, void* d_ws, size_t ws_size,
                              hipStream_t stream) {
    const int*   y_true  = (const int*)  d_in[0];
    const float* y_pred  = (const float*)d_in[1];
    const int*   in_len  = (const int*)  d_in[2];
    const int*   lab_len = (const int*)  d_in[3];
    float*       out     = (float*)      d_out;

    ctc_wave<<<dim3(128), dim3(64), 0, stream>>>(y_true, y_pred, in_len, lab_len, out);
}

// Round 5
// 490.391 us; speedup vs baseline: 1.5290x; 1.5290x over previous
//
#include <hip/hip_runtime.h>

// CTC batch cost (keras ctc_batch_cost), forward alpha recursion.
// B=128, T=512, C=1024, L=64, S=2L+1=129, blank = C-1.
//
// R5: two-phase. The per-step 64-lane *gather* (y_pred[b,t,cls[lane]]) was
// the bottleneck when fused into the serial recursion: one wave can't keep
// enough gather lines in flight (miss-buffer bound, ~2246 cy/step measured).
// Phase 1 (ctc_emit, 8192 blocks) does all gathers with throughput
// parallelism and writes a dense E[b][t][65] table (log2-domain emissions)
// into d_ws. Phase 2 (ctc_rec, one wave per batch) runs the recursion
// reading one coalesced 260B row per step — latency trivially hidden by a
// depth-8 ring of coalesced loads.
//
// Recursion runs in log2 domain (v_exp_f32/v_log_f32 are base-2 HW ops);
// ln-domain alpha = log2-domain alpha * ln2 exactly, restored at the end.
//
// Lane i owns extended states {2i, 2i+1}; lane 63 also owns state 128.
// Cross-lane dep (state 2i-1 = prev lane's hi) via DPP wave_shr:1.
//
// Inputs: d_in[0] y_true i32[B,L]; d_in[1] y_pred f32[B,T,C];
//         d_in[2] input_length i32[B,1]; d_in[3] label_length i32[B,1].
// Output: float [B,1].

constexpr int Tmax   = 512;
constexpr int Cch    = 1024;
constexpr int Lm     = 64;
constexpr int BLANKC = Cch - 1;
constexpr int ES     = 65;    // E-row stride: 64 label emissions + 1 blank
constexpr int TS     = 8;     // timesteps per emit block
constexpr int PF2    = 8;     // recursion prefetch depth (coalesced rows)

#define NEGF (-1e9f)
#define EPSF (1e-7f)
#define LN2F (0.69314718055994530942f)

__device__ __forceinline__ float wave_shr1(float src, float fill) {
    int r = __builtin_amdgcn_update_dpp(__float_as_int(fill), __float_as_int(src),
                                        0x138, 0xf, 0xf, false);
    return __int_as_float(r);
}
__device__ __forceinline__ float lae2(float a, float b) {
    float m = fmaxf(a, b);
    return m + __builtin_log2f(__builtin_exp2f(a - m) + __builtin_exp2f(b - m));
}
__device__ __forceinline__ float lse3_2(float a, float b, float c) {
    float m = fmaxf(fmaxf(a, b), c);
    return m + __builtin_log2f(__builtin_exp2f(a - m) +
                               __builtin_exp2f(b - m) +
                               __builtin_exp2f(c - m));
}
__device__ __forceinline__ int clampi(int v, int lo, int hi) {
    return v < lo ? lo : (v > hi ? hi : v);
}

// ---------------- Phase 1: emission gather (throughput) ----------------
__global__ __launch_bounds__(64, 1) void ctc_emit(
    const int*   __restrict__ y_true,
    const float* __restrict__ y_pred,
    const int*   __restrict__ in_len,
    float*       __restrict__ E)
{
    const int lane = threadIdx.x;
    const int b    = blockIdx.x;            // 0..B-1
    const int t0   = blockIdx.y * TS;       // chunk start

    const int Tb = clampi(in_len[b], 0, Tmax);
    if (t0 >= Tb) return;
    const int nt = (Tb - t0) < TS ? (Tb - t0) : TS;

    const int cls = y_true[b * Lm + lane];
    const float* __restrict__ base = y_pred + (size_t)b * Tmax * Cch;

    // issue all gathers first (ILP), then convert+store
    float pc[TS], pb[TS];
#pragma unroll
    for (int i = 0; i < TS; ++i) {
        const int t = t0 + (i < nt ? i : (nt - 1));
        const float* row = base + (size_t)t * Cch;
        pc[i] = row[cls];
        pb[i] = row[BLANKC];
    }
#pragma unroll
    for (int i = 0; i < TS; ++i) {
        if (i >= nt) break;
        const size_t idx = ((size_t)b * Tmax + (t0 + i)) * ES;
        E[idx + lane] = __builtin_log2f(pc[i] + EPSF);
        if (lane == 0) E[idx + 64] = __builtin_log2f(pb[i] + EPSF);
    }
}

// ---------------- Phase 2: alpha recursion (latency) ----------------
__global__ __launch_bounds__(64, 1) void ctc_rec(
    const int*   __restrict__ y_true,
    const int*   __restrict__ in_len,
    const int*   __restrict__ lab_len,
    const float* __restrict__ E,
    float*       __restrict__ out)
{
    const int b    = blockIdx.x;
    const int lane = threadIdx.x;

    const int cls = y_true[b * Lm + lane];
    const int Tb  = clampi(in_len[b], 0, Tmax);
    const int lb  = clampi(lab_len[b], 0, Lm);

    const int  cls_prev = __shfl_up(cls, 1, 64);
    const bool skip     = (lane >= 1) && (cls != cls_prev);

    const bool val_lo = (lane <= lb);        // state 2*lane
    const bool val_hi = (lane <  lb);        // state 2*lane+1
    const bool val_ex = (lb == Lm);          // state 128 (lane 63 only)

    float a_lo = (lane == 0) ? 0.f : NEGF;
    float a_hi = NEGF;
    float a_ex = NEGF;

    const float* __restrict__ eb = E + (size_t)b * Tmax * ES;

    // coalesced prefetch ring over E rows (values already log2-domain)
    float pf_c[PF2], pf_b[PF2];
#pragma unroll
    for (int i = 0; i < PF2; ++i) {
        const float* row = eb + (size_t)i * ES;   // i < PF2 <= Tmax
        pf_c[i] = row[lane];
        pf_b[i] = row[64];
    }

    for (int t0 = 0; t0 < Tb; t0 += PF2) {
#pragma unroll
        for (int i = 0; i < PF2; ++i) {
            const int t = t0 + i;
            if (t >= Tb) break;              // Tb wave-uniform

            const float e_c = pf_c[i];
            const float e_b = pf_b[i];

            // refill slot for t+PF2 (row clamped; rows >= Tb may be poison
            // but are never consumed)
            {
                int tp = t + PF2; int tr = tp < Tmax ? tp : Tmax - 1;
                const float* row = eb + (size_t)tr * ES;
                pf_c[i] = row[lane];
                pf_b[i] = row[64];
            }

            const float p_hi = wave_shr1(a_hi, NEGF);   // state 2i-1

            float n_lo = e_b + lae2(a_lo, p_hi);
            float n_hi = e_c + lse3_2(a_hi, a_lo, skip ? p_hi : NEGF);
            float n_ex = e_b + lae2(a_ex, a_hi);

            a_lo = val_lo ? n_lo : NEGF;
            a_hi = val_hi ? n_hi : NEGF;
            a_ex = val_ex ? n_ex : NEGF;
        }
    }

    const float a_end_blank = (lb == Lm) ? __shfl(a_ex, 63, 64)
                                         : __shfl(a_lo, lb, 64);
    const int   el_lane     = (lb >= 1) ? (lb - 1) : 0;
    const float a_end_label = (lb >= 1) ? __shfl(a_hi, el_lane, 64)
                                        : __shfl(a_lo, 0, 64);

    if (lane == 0) {
        out[b] = -LN2F * lae2(a_end_blank, a_end_label);
    }
}

// ---------------- Fallback: fused single-kernel (R4, correct) ----------------
__global__ __launch_bounds__(64, 1) void ctc_fused(
    const int*   __restrict__ y_true,
    const float* __restrict__ y_pred,
    const int*   __restrict__ in_len,
    const int*   __restrict__ lab_len,
    float*       __restrict__ out)
{
    const int b    = blockIdx.x;
    const int lane = threadIdx.x;
    const int cls  = y_true[b * Lm + lane];
    const int Tb   = clampi(in_len[b], 0, Tmax);
    const int lb   = clampi(lab_len[b], 0, Lm);

    const int  cls_prev = __shfl_up(cls, 1, 64);
    const bool skip     = (lane >= 1) && (cls != cls_prev);
    const bool val_lo = (lane <= lb);
    const bool val_hi = (lane <  lb);
    const bool val_ex = (lb == Lm);

    float a_lo = (lane == 0) ? 0.f : NEGF;
    float a_hi = NEGF, a_ex = NEGF;
    const float* __restrict__ base = y_pred + (size_t)b * Tmax * Cch;

    constexpr int PF = 8;
    float pf_c[PF], pf_b[PF];
#pragma unroll
    for (int i = 0; i < PF; ++i) {
        const float* row = base + (size_t)i * Cch;
        pf_c[i] = row[cls]; pf_b[i] = row[BLANKC];
    }
    for (int t0 = 0; t0 < Tb; t0 += PF) {
#pragma unroll
        for (int i = 0; i < PF; ++i) {
            const int t = t0 + i;
            if (t >= Tb) break;
            const float e_c = __builtin_log2f(pf_c[i] + EPSF);
            const float e_b = __builtin_log2f(pf_b[i] + EPSF);
            { int tp = t + PF; int tr = tp < Tmax ? tp : Tmax - 1;
              const float* row = base + (size_t)tr * Cch;
              pf_c[i] = row[cls]; pf_b[i] = row[BLANKC]; }
            const float p_hi = wave_shr1(a_hi, NEGF);
            float n_lo = e_b + lae2(a_lo, p_hi);
            float n_hi = e_c + lse3_2(a_hi, a_lo, skip ? p_hi : NEGF);
            float n_ex = e_b + lae2(a_ex, a_hi);
            a_lo = val_lo ? n_lo : NEGF;
            a_hi = val_hi ? n_hi : NEGF;
            a_ex = val_ex ? n_ex : NEGF;
        }
    }
    const float a_end_blank = (lb == Lm) ? __shfl(a_ex, 63, 64)
                                         : __shfl(a_lo, lb, 64);
    const int   el_lane     = (lb >= 1) ? (lb - 1) : 0;
    const float a_end_label = (lb >= 1) ? __shfl(a_hi, el_lane, 64)
                                        : __shfl(a_lo, 0, 64);
    if (lane == 0) out[b] = -LN2F * lae2(a_end_blank, a_end_label);
}

extern "C" void kernel_launch(void* const* d_in, const int* in_sizes, int n_in,
                              void* d_out, int out_size, void* d_ws, size_t ws_size,
                              hipStream_t stream) {
    const int*   y_true  = (const int*)  d_in[0];
    const float* y_pred  = (const float*)d_in[1];
    const int*   in_len  = (const int*)  d_in[2];
    const int*   lab_len = (const int*)  d_in[3];
    float*       out     = (float*)      d_out;

    const size_t need = (size_t)128 * Tmax * ES * sizeof(float);  // ~17 MB
    if (ws_size >= need) {
        float* E = (float*)d_ws;
        ctc_emit<<<dim3(128, Tmax / TS), dim3(64), 0, stream>>>(
            y_true, y_pred, in_len, E);
        ctc_rec<<<dim3(128), dim3(64), 0, stream>>>(
            y_true, in_len, lab_len, E, out);
    } else {
        ctc_fused<<<dim3(128), dim3(64), 0, stream>>>(
            y_true, y_pred, in_len, lab_len, out);
    }
}

// Round 6
// 415.356 us; speedup vs baseline: 1.8053x; 1.1807x over previous
//
#include <hip/hip_runtime.h>

// CTC batch cost (keras ctc_batch_cost), forward alpha recursion.
// B=128, T=512, C=1024, L=64, S=2L+1=129, blank = C-1.
//
// R6: single kernel, one 1024-thread block (16 waves) per batch element.
//   waves 1..15: gather emissions y_pred[b,t,cls[lane]] (+ blank) for a
//     64-timestep chunk, convert to log2 domain, store into LDS
//     (double-buffered, 2 x 64 x 66 floats = 34 KB).
//   wave 0:      runs the serial alpha recursion out of LDS for chunk c
//     while waves 1..15 gather chunk c+1. One __syncthreads per chunk.
// This removes R5's global E round-trip (cross-kernel, cross-XCD L2) and
// overlaps all gather latency under the recursion's serial chain.
//
// Recursion (verified exact in R4/R5, absmax=0): lane i owns extended
// states {2i, 2i+1}; lane 63 also owns state 128. Cross-lane dep
// (state 2i-1 = prev lane's hi) via DPP wave_shr:1. Log2 domain
// (v_exp_f32/v_log_f32 are base-2 HW ops); ln alpha = log2 alpha * ln2
// exactly, restored at the final loss.
//
// Inputs: d_in[0] y_true i32[B,L]; d_in[1] y_pred f32[B,T,C];
//         d_in[2] input_length i32[B,1]; d_in[3] label_length i32[B,1].
// Output: float [B,1].

constexpr int Tmax   = 512;
constexpr int Cch    = 1024;
constexpr int Lm     = 64;
constexpr int BLANKC = Cch - 1;
constexpr int CH     = 64;           // timesteps per chunk
constexpr int NCH    = Tmax / CH;    // 8
constexpr int ROW    = 66;           // LDS row stride: 64 labels + blank + pad

#define NEGF (-1e9f)
#define EPSF (1e-7f)
#define LN2F (0.69314718055994530942f)

__device__ __forceinline__ float wave_shr1(float src, float fill) {
    int r = __builtin_amdgcn_update_dpp(__float_as_int(fill), __float_as_int(src),
                                        0x138, 0xf, 0xf, false);
    return __int_as_float(r);
}
__device__ __forceinline__ float lae2(float a, float b) {
    float m = fmaxf(a, b);
    return m + __builtin_log2f(__builtin_exp2f(a - m) + __builtin_exp2f(b - m));
}
__device__ __forceinline__ float lse3_2(float a, float b, float c) {
    float m = fmaxf(fmaxf(a, b), c);
    return m + __builtin_log2f(__builtin_exp2f(a - m) +
                               __builtin_exp2f(b - m) +
                               __builtin_exp2f(c - m));
}
__device__ __forceinline__ int clampi(int v, int lo, int hi) {
    return v < lo ? lo : (v > hi ? hi : v);
}

__global__ __launch_bounds__(1024, 1) void ctc_onekernel(
    const int*   __restrict__ y_true,
    const float* __restrict__ y_pred,
    const int*   __restrict__ in_len,
    const int*   __restrict__ lab_len,
    float*       __restrict__ out)
{
    const int b    = blockIdx.x;
    const int tid  = threadIdx.x;
    const int wave = tid >> 6;
    const int lane = tid & 63;

    __shared__ float Ebuf[2][CH * ROW];     // 33.8 KB

    const int cls = y_true[b * Lm + lane];  // label of odd state 2*lane+1
    const int Tb  = clampi(in_len[b], 0, Tmax);
    const int lb  = clampi(lab_len[b], 0, Lm);
    const float* __restrict__ base = y_pred + (size_t)b * Tmax * Cch;

    // gather chunk c into Ebuf[c&1]; waves 1..15 split the 64 timesteps.
    // All loads issued before any LDS write (single HBM round trip / chunk).
    auto gather = [&](int c) {
        const int tbase = c * CH;
        const int tt0   = wave - 1;         // 0..14
        float pc[5], pb[5];
#pragma unroll
        for (int k = 0; k < 5; ++k) {
            const int tt = tt0 + 15 * k;
            if (tt < CH) {
                const float* row = base + (size_t)(tbase + tt) * Cch;
                pc[k] = row[cls];
                pb[k] = row[BLANKC];        // uniform address -> broadcast
            }
        }
#pragma unroll
        for (int k = 0; k < 5; ++k) {
            const int tt = tt0 + 15 * k;
            if (tt < CH) {
                float* dst = &Ebuf[c & 1][tt * ROW];
                dst[lane] = __builtin_log2f(pc[k] + EPSF);
                if (lane == 0) dst[64] = __builtin_log2f(pb[k] + EPSF);
            }
        }
    };

    // recursion state (wave 0; harmless elsewhere)
    const int  cls_prev = __shfl_up(cls, 1, 64);
    const bool skip     = (lane >= 1) && (cls != cls_prev);
    const bool val_lo   = (lane <= lb);     // state 2*lane
    const bool val_hi   = (lane <  lb);     // state 2*lane+1
    const bool val_ex   = (lb == Lm);       // state 128 (lane 63)

    float a_lo = (lane == 0) ? 0.f : NEGF;  // virtual alpha_{-1}
    float a_hi = NEGF;
    float a_ex = NEGF;

    if (wave != 0) gather(0);
    __syncthreads();

    for (int c = 0; c < NCH; ++c) {
        if (wave == 0) {
            const int tbase = c * CH;
            if (tbase < Tb) {
                const int steps = (Tb - tbase) < CH ? (Tb - tbase) : CH;
                const float* eb = Ebuf[c & 1];
                // depth-4 register ring over LDS rows (chunk fully gathered,
                // so rows [0,CH) are always valid to prefetch)
                float rc[4], rb[4];
#pragma unroll
                for (int i = 0; i < 4; ++i) {
                    rc[i] = eb[i * ROW + lane];
                    rb[i] = eb[i * ROW + 64];
                }
                for (int i0 = 0; i0 < CH; i0 += 4) {
#pragma unroll
                    for (int j = 0; j < 4; ++j) {
                        const int i = i0 + j;
                        if (i >= steps) break;
                        const float e_c = rc[j];
                        const float e_b = rb[j];
                        const int tn = i + 4;
                        if (tn < CH) {
                            rc[j] = eb[tn * ROW + lane];
                            rb[j] = eb[tn * ROW + 64];
                        }
                        const float p_hi = wave_shr1(a_hi, NEGF); // state 2i-1
                        float n_lo = e_b + lae2(a_lo, p_hi);
                        float n_hi = e_c + lse3_2(a_hi, a_lo, skip ? p_hi : NEGF);
                        float n_ex = e_b + lae2(a_ex, a_hi);
                        a_lo = val_lo ? n_lo : NEGF;
                        a_hi = val_hi ? n_hi : NEGF;
                        a_ex = val_ex ? n_ex : NEGF;
                    }
                    if (i0 + 4 >= steps) break;
                }
            }
        } else {
            // gather chunk c+1 iff the recursion will consume it
            if (c + 1 < NCH && (c + 1) * CH < Tb) gather(c + 1);
        }
        __syncthreads();   // uniform: all 16 waves, every iteration
    }

    if (wave == 0) {
        const float a_end_blank = (lb == Lm) ? __shfl(a_ex, 63, 64)
                                             : __shfl(a_lo, lb, 64);
        const int   el_lane     = (lb >= 1) ? (lb - 1) : 0;
        const float a_end_label = (lb >= 1) ? __shfl(a_hi, el_lane, 64)
                                            : __shfl(a_lo, 0, 64);
        if (lane == 0) {
            out[b] = -LN2F * lae2(a_end_blank, a_end_label);
        }
    }
}

extern "C" void kernel_launch(void* const* d_in, const int* in_sizes, int n_in,
                              void* d_out, int out_size, void* d_ws, size_t ws_size,
                              hipStream_t stream) {
    const int*   y_true  = (const int*)  d_in[0];
    const float* y_pred  = (const float*)d_in[1];
    const int*   in_len  = (const int*)  d_in[2];
    const int*   lab_len = (const int*)  d_in[3];
    float*       out     = (float*)      d_out;

    ctc_onekernel<<<dim3(128), dim3(1024), 0, stream>>>(
        y_true, y_pred, in_len, lab_len, out);
}